// Round 18
// baseline (725.244 us; speedup 1.0000x reference)
//
#include <hip/hip_runtime.h>
#include <hip/hip_bf16.h>
#include <math.h>

#define S_LEN 1024
#define HDIM  768
#define NPROC 4
#define VOCAB 50257
#define KSTEPS 4

typedef __attribute__((ext_vector_type(4))) float f32x4;
typedef __attribute__((ext_vector_type(8))) short bf16x8;
typedef __attribute__((ext_vector_type(4))) short short4v;

static __device__ __forceinline__ ushort f2bf(float f) {
  union { __hip_bfloat16 b; ushort u; } cv;
  cv.b = __float2bfloat16(f);
  return cv.u;
}

#define GLOAD16(gp, lp) __builtin_amdgcn_global_load_lds( \
    (const __attribute__((address_space(1))) unsigned int*)(gp), \
    (__attribute__((address_space(3))) unsigned int*)(lp), 16, 0, 0)

// ---------------- prep: weight converts (lmw+W1+W2) + fused LN(k=0), one dispatch --------
__global__ __launch_bounds__(256) void prep_weights(
    const float* __restrict__ lmw, const float* __restrict__ W1,
    const float* __restrict__ W2, ushort* __restrict__ lm_bf,
    ushort* __restrict__ w1_bf, ushort* __restrict__ w2_bf,
    const float* __restrict__ hidden, const int* __restrict__ mask,
    const float* __restrict__ alphap, const float* __restrict__ gamma,
    const float* __restrict__ beta, ushort* __restrict__ normed) {
  const int LM4 = VOCAB * HDIM / 4;
  const int W4  = HDIM * HDIM / 4;
  const int LMB = (LM4 + 255) / 256;
  const int WB  = (W4 + 255) / 256;
  const int bid = blockIdx.x;
  const int tid = threadIdx.x;
  __shared__ float rs_[4], rq_[4];
  if (bid < LMB + 2 * WB) {
    const float* in; ushort* out; int n4, i;
    if (bid < LMB)           { in = lmw; out = lm_bf; n4 = LM4; i = bid * 256 + tid; }
    else if (bid < LMB + WB) { in = W1;  out = w1_bf; n4 = W4;  i = (bid - LMB) * 256 + tid; }
    else                     { in = W2;  out = w2_bf; n4 = W4;  i = (bid - LMB - WB) * 256 + tid; }
    if (i >= n4) return;
    f32x4 v = ((const f32x4*)in)[i];
    short4v o;
#pragma unroll
    for (int j = 0; j < 4; j++) o[j] = (short)f2bf(v[j]);
    ((short4v*)out)[i] = o;
  } else {
    // ---- LN for k=0 on hidden ----
    const int s = bid - (LMB + 2 * WB);
    const float mk = (float)mask[s];
    const float a1 = 1.0f + alphap[0];
    float merged[3];
    float lsum = 0.f, lsq = 0.f;
#pragma unroll
    for (int e = 0; e < 3; e++) {
      const int h = tid + e * 256;
      float mg = hidden[(size_t)s * HDIM + h] * mk * a1;
      merged[e] = mg;
      lsum += mg;
      lsq += mg * mg;
    }
#pragma unroll
    for (int off = 32; off > 0; off >>= 1) {
      lsum += __shfl_down(lsum, off, 64);
      lsq  += __shfl_down(lsq, off, 64);
    }
    const int wv = tid >> 6, ln = tid & 63;
    if (ln == 0) { rs_[wv] = lsum; rq_[wv] = lsq; }
    __syncthreads();
    const float ts = rs_[0] + rs_[1] + rs_[2] + rs_[3];
    const float tq = rq_[0] + rq_[1] + rq_[2] + rq_[3];
    const float mu = ts * (1.f / HDIM);
    const float var = tq * (1.f / HDIM) - mu * mu;
    const float rstd = rsqrtf(var + 1e-5f);
#pragma unroll
    for (int e = 0; e < 3; e++) {
      const int h = tid + e * 256;
      float nv = (merged[e] - mu) * rstd * gamma[h] + beta[h];
      normed[(size_t)s * HDIM + h] = f2bf(nv);
    }
  }
}

// ---------------- flat broadcast logits -> plogits[0..3] ----------------
__global__ __launch_bounds__(256) void bcast_logits(
    const float* __restrict__ src, float* __restrict__ dst) {
  const size_t n4 = (size_t)S_LEN * VOCAB / 4;
  for (size_t i = (size_t)blockIdx.x * 256 + threadIdx.x; i < n4;
       i += (size_t)gridDim.x * 256) {
    f32x4 v = ((const f32x4*)src)[i];
#pragma unroll
    for (int p = 0; p < NPROC; p++)
      ((f32x4*)dst)[(size_t)p * n4 + i] = v;
  }
}

// ---------------- P=1 merge + LayerNorm -> bf16 (k>0, reads st1) ----------------
__global__ __launch_bounds__(256) void merge_ln_p1(
    const float* __restrict__ src, const int* __restrict__ mask,
    const float* __restrict__ alphap, const float* __restrict__ gamma,
    const float* __restrict__ beta, ushort* __restrict__ normed) {
  const int s = blockIdx.x;
  const int tid = threadIdx.x;
  const float mk = (float)mask[s];
  const float a1 = 1.0f + alphap[0];
  float merged[3];
  float lsum = 0.f, lsq = 0.f;
#pragma unroll
  for (int e = 0; e < 3; e++) {
    const int h = tid + e * 256;
    float mg = src[(size_t)s * HDIM + h] * mk * a1;
    merged[e] = mg;
    lsum += mg;
    lsq += mg * mg;
  }
#pragma unroll
  for (int off = 32; off > 0; off >>= 1) {
    lsum += __shfl_down(lsum, off, 64);
    lsq  += __shfl_down(lsq, off, 64);
  }
  __shared__ float rs_[4], rq_[4];
  const int wv = tid >> 6, ln = tid & 63;
  if (ln == 0) { rs_[wv] = lsum; rq_[wv] = lsq; }
  __syncthreads();
  const float ts = rs_[0] + rs_[1] + rs_[2] + rs_[3];
  const float tq = rq_[0] + rq_[1] + rq_[2] + rq_[3];
  const float mu = ts * (1.f / HDIM);
  const float var = tq * (1.f / HDIM) - mu * mu;
  const float rstd = rsqrtf(var + 1e-5f);
#pragma unroll
  for (int e = 0; e < 3; e++) {
    const int h = tid + e * 256;
    float nv = (merged[e] - mu) * rstd * gamma[h] + beta[h];
    normed[(size_t)s * HDIM + h] = f2bf(nv);
  }
}

// ---------------- MLP GEMM  C[M=1024,N=768] = A * B^T, 128x64 tile, BK=32, ring-3 -------
// MODE 0: +b1, exact GELU -> bf16 h
// MODE 1: +b2, ns=(src*mask+C)*mask -> st1; last step: bf16 out + states fanout
template <int MODE>
__global__ __launch_bounds__(256, 4) void gemm_mlp(
    const ushort* __restrict__ A, const ushort* __restrict__ B,
    const float* __restrict__ bias, ushort* __restrict__ out_bf,
    const float* __restrict__ src, float* __restrict__ dst,
    float* __restrict__ states, const int* __restrict__ mask) {
  __shared__ __align__(16) ushort lsA[3][4096];
  __shared__ __align__(16) ushort lsB[3][2048];
  const int tid = threadIdx.x;
  const int bx = blockIdx.x;
  const int mt = bx & 7;
  const int nt = bx >> 3;
  const int wv = tid >> 6, lane = tid & 63;
  const int wm = wv >> 1, wn = wv & 1;
  const int g = lane >> 4, lr = lane & 15;

  f32x4 acc[4][2];
#pragma unroll
  for (int i = 0; i < 4; i++)
#pragma unroll
    for (int j = 0; j < 2; j++) acc[i][j] = (f32x4){0.f, 0.f, 0.f, 0.f};

  const int koff = (tid & 3) * 8;
  const int arow0 = mt * 128 + (tid >> 2);
  const ushort* gA0 = A + (size_t)arow0 * HDIM + koff;
  const ushort* gA1 = gA0 + (size_t)64 * HDIM;
  const ushort* gB0 = B + (size_t)(nt * 64 + (tid >> 2)) * HDIM + koff;
  const int dstl = (tid >> 2) * 32 + (tid & 3) * 8;

#define STAGE(kt, buf) do {                      \
    const int o_ = (kt) * 32;                    \
    GLOAD16(gA0 + o_, &lsA[buf][dstl]);          \
    GLOAD16(gA1 + o_, &lsA[buf][2048 + dstl]);   \
    GLOAD16(gB0 + o_, &lsB[buf][dstl]);          \
  } while (0)

  constexpr int NT = HDIM / 32;  // 24
  STAGE(0, 0);
  STAGE(1, 1);
  STAGE(2, 2);
  int cur = 0;
  for (int kt = 0; kt < NT; ++kt) {
    if (kt < NT - 2)       asm volatile("s_waitcnt vmcnt(6)" ::: "memory");
    else if (kt == NT - 2) asm volatile("s_waitcnt vmcnt(3)" ::: "memory");
    else                   asm volatile("s_waitcnt vmcnt(0)" ::: "memory");
    __builtin_amdgcn_s_barrier();
    __builtin_amdgcn_sched_barrier(0);
    bf16x8 af[4], bfr[2];
#pragma unroll
    for (int mi = 0; mi < 4; mi++)
      af[mi] = *(const bf16x8*)(&lsA[cur][(wm * 64 + mi * 16 + lr) * 32 + g * 8]);
#pragma unroll
    for (int ni = 0; ni < 2; ni++)
      bfr[ni] = *(const bf16x8*)(&lsB[cur][(wn * 32 + ni * 16 + lr) * 32 + g * 8]);
    asm volatile("s_waitcnt lgkmcnt(0)" ::: "memory");
    __builtin_amdgcn_sched_barrier(0);
    __builtin_amdgcn_s_setprio(1);
#pragma unroll
    for (int mi = 0; mi < 4; mi++)
#pragma unroll
      for (int ni = 0; ni < 2; ni++)
        acc[mi][ni] = __builtin_amdgcn_mfma_f32_16x16x32_bf16(af[mi], bfr[ni], acc[mi][ni], 0, 0, 0);
    __builtin_amdgcn_s_setprio(0);
    __builtin_amdgcn_s_barrier();
    __builtin_amdgcn_sched_barrier(0);
    if (kt + 3 < NT) STAGE(kt + 3, cur);
    cur = (cur == 2) ? 0 : cur + 1;
  }
#undef STAGE

#pragma unroll
  for (int mi = 0; mi < 4; mi++) {
    const int mrow = mt * 128 + wm * 64 + mi * 16 + g * 4;
#pragma unroll
    for (int ni = 0; ni < 2; ni++) {
      const int ncol = nt * 64 + wn * 32 + ni * 16 + lr;
      const float bv = bias[ncol];
      if (MODE == 0) {
#pragma unroll
        for (int j = 0; j < 4; j++) {
          float x = acc[mi][ni][j] + bv;
          float ge = 0.5f * x * (1.f + erff(x * 0.70710678118654752f));
          out_bf[(size_t)(mrow + j) * HDIM + ncol] = f2bf(ge);
        }
      } else {
#pragma unroll
        for (int j = 0; j < 4; j++) {
          const int m = mrow + j;   // m == s at P=1
          const float mk = (float)mask[m];
          const size_t idx = (size_t)m * HDIM + ncol;
          const float mut = src[idx] * mk;
          const float ns = (mut + acc[mi][ni][j] + bv) * mk;
          if (out_bf) {
            out_bf[idx] = f2bf(ns);
#pragma unroll
            for (int p = 0; p < NPROC; p++)
              states[(size_t)p * S_LEN * HDIM + idx] = ns;
          } else {
            dst[idx] = ns;
          }
        }
      }
    }
  }
}

// ---------------- LM-head GEMM: barrier-free pure-TLP wave-level kernel -----------------
// C[1024, 50257] = A[1024,768] * B[50257,768]^T. Each WAVE computes an independent 64x64
// tile: operands loaded global->registers (A L2-resident 1.5MB; B L3-resident 77MB), no
// LDS, no barriers. Latency hidden by occupancy (acc[4][4]=64 VGPR -> ~3 waves/SIMD).
// Block = 4 waves sharing one m-tile (A reuse via L1/L2). Grid = 16 mt x 197 ntg.
__global__ __launch_bounds__(256) void gemm_lm_tlp(
    const ushort* __restrict__ A, const ushort* __restrict__ B,
    float* __restrict__ logits) {
  const int tid = threadIdx.x;
  const int wv = tid >> 6, lane = tid & 63;
  const int g = lane >> 4, lr = lane & 15;
  const int bx = blockIdx.x;
  const int mt = bx & 15;                 // 16 m-tiles of 64
  const int ntg = bx >> 4;                // 197 groups of 4 n-tiles
  const int nt = ntg * 4 + wv;            // this wave's 64-col n-tile
  const int m0 = mt * 64;
  const int n0 = nt * 64;

  f32x4 acc[4][4];
#pragma unroll
  for (int i = 0; i < 4; i++)
#pragma unroll
    for (int j = 0; j < 4; j++) acc[i][j] = (f32x4){0.f, 0.f, 0.f, 0.f};

  // A fragment rows: m0 + mi*16 + lr, k-slot g (verified session convention)
  const ushort* Ab = A + (size_t)(m0 + lr) * HDIM + g * 8;
  // B fragment rows (vocab): n0 + ni*16 + lr, clamped
  const ushort* Bb[4];
#pragma unroll
  for (int ni = 0; ni < 4; ni++) {
    int r = n0 + ni * 16 + lr;
    if (r >= VOCAB) r = VOCAB - 1;
    Bb[ni] = B + (size_t)r * HDIM + g * 8;
  }

  for (int kt = 0; kt < HDIM / 32; ++kt) {
    bf16x8 af[4], bfr[4];
#pragma unroll
    for (int mi = 0; mi < 4; mi++)
      af[mi] = *(const bf16x8*)(Ab + (size_t)mi * 16 * HDIM + kt * 32);
#pragma unroll
    for (int ni = 0; ni < 4; ni++)
      bfr[ni] = *(const bf16x8*)(Bb[ni] + kt * 32);
#pragma unroll
    for (int mi = 0; mi < 4; mi++)
#pragma unroll
      for (int ni = 0; ni < 4; ni++)
        acc[mi][ni] = __builtin_amdgcn_mfma_f32_16x16x32_bf16(af[mi], bfr[ni], acc[mi][ni], 0, 0, 0);
  }

#pragma unroll
  for (int mi = 0; mi < 4; mi++) {
    const int row0 = m0 + mi * 16 + g * 4;
#pragma unroll
    for (int ni = 0; ni < 4; ni++) {
      const int col = n0 + ni * 16 + lr;
      if (col < VOCAB) {
#pragma unroll
        for (int j = 0; j < 4; j++)
          logits[(size_t)(row0 + j) * VOCAB + col] = acc[mi][ni][j];
      }
    }
  }
}

extern "C" void kernel_launch(void* const* d_in, const int* in_sizes, int n_in,
                              void* d_out, int out_size, void* d_ws, size_t ws_size,
                              hipStream_t stream) {
  const float* hidden = (const float*)d_in[0];
  const int*   mask   = (const int*)d_in[1];
  const float* alphap = (const float*)d_in[2];
  const float* gamma  = (const float*)d_in[3];
  const float* beta   = (const float*)d_in[4];
  const float* W1     = (const float*)d_in[5];
  const float* b1     = (const float*)d_in[6];
  const float* W2     = (const float*)d_in[7];
  const float* b2     = (const float*)d_in[8];
  const float* lmw    = (const float*)d_in[9];

  float* logits  = (float*)d_out;
  float* plogits = logits + (size_t)S_LEN * VOCAB;
  float* states  = plogits + (size_t)NPROC * S_LEN * VOCAB;

  uint8_t* ws = (uint8_t*)d_ws;
  ushort* lm_bf  = (ushort*)ws;                       // 77,194,752 B
  ushort* w1_bf  = (ushort*)(ws + 77194752);          // 1,179,648 B
  ushort* w2_bf  = (ushort*)(ws + 78374400);          // 1,179,648 B
  ushort* nrm_bf = (ushort*)(ws + 79554048);          // 1,572,864 B
  ushort* h_bf   = (ushort*)(ws + 81126912);          // 1,572,864 B
  ushort* a_bf   = (ushort*)(ws + 82699776);          // 1,572,864 B
  float*  st1    = (float*) (ws + 84272640);          // 3,145,728 B
  if (ws_size < 87418368) return;

  const int LMB = (VOCAB * HDIM / 4 + 255) / 256, WB = (HDIM * HDIM / 4 + 255) / 256;
  prep_weights<<<LMB + 2 * WB + S_LEN, 256, 0, stream>>>(
      lmw, W1, W2, lm_bf, w1_bf, w2_bf, hidden, mask, alphap, gamma, beta, nrm_bf);

  for (int k = 0; k < KSTEPS; k++) {
    const float* src = (k == 0) ? hidden : st1;
    if (k > 0)
      merge_ln_p1<<<S_LEN, 256, 0, stream>>>(src, mask, alphap, gamma, beta, nrm_bf);
    gemm_mlp<0><<<(HDIM / 64) * 8, 256, 0, stream>>>(
        nrm_bf, w1_bf, b1, h_bf, nullptr, nullptr, nullptr, mask);
    gemm_mlp<1><<<(HDIM / 64) * 8, 256, 0, stream>>>(
        h_bf, w2_bf, b2, (k == KSTEPS - 1) ? (ushort*)a_bf : nullptr,
        src, st1, states, mask);
  }
  // 786 n-tiles of 64 -> 197 groups of 4 waves; grid = 16 x 197
  gemm_lm_tlp<<<16 * 197, 256, 0, stream>>>(a_bf, lm_bf, logits);
  bcast_logits<<<2048, 256, 0, stream>>>(logits, plogits);
}

// Round 19
// 539.688 us; speedup vs baseline: 1.3438x; 1.3438x over previous
//
#include <hip/hip_runtime.h>
#include <hip/hip_bf16.h>
#include <math.h>

#define S_LEN 1024
#define HDIM  768
#define NPROC 4
#define VOCAB 50257
#define KSTEPS 4

typedef __attribute__((ext_vector_type(4))) float f32x4;
typedef __attribute__((ext_vector_type(8))) short bf16x8;
typedef __attribute__((ext_vector_type(4))) short short4v;

static __device__ __forceinline__ ushort f2bf(float f) {
  union { __hip_bfloat16 b; ushort u; } cv;
  cv.b = __float2bfloat16(f);
  return cv.u;
}

#define GLOAD16(gp, lp) __builtin_amdgcn_global_load_lds( \
    (const __attribute__((address_space(1))) unsigned int*)(gp), \
    (__attribute__((address_space(3))) unsigned int*)(lp), 16, 0, 0)

// ---------------- merged f32 -> bf16 weight convert (lmw + W1 + W2, one dispatch) --------
__global__ void prep_weights(const float* __restrict__ lmw, const float* __restrict__ W1,
                             const float* __restrict__ W2, ushort* __restrict__ lm_bf,
                             ushort* __restrict__ w1_bf, ushort* __restrict__ w2_bf) {
  const int LM4 = VOCAB * HDIM / 4;
  const int W4  = HDIM * HDIM / 4;
  const int LMB = (LM4 + 255) / 256;
  const int WB  = (W4 + 255) / 256;
  const int bid = blockIdx.x;
  const float* in; ushort* out; int n4, i;
  if (bid < LMB)           { in = lmw; out = lm_bf; n4 = LM4; i = bid * 256 + threadIdx.x; }
  else if (bid < LMB + WB) { in = W1;  out = w1_bf; n4 = W4;  i = (bid - LMB) * 256 + threadIdx.x; }
  else                     { in = W2;  out = w2_bf; n4 = W4;  i = (bid - LMB - WB) * 256 + threadIdx.x; }
  if (i >= n4) return;
  f32x4 v = ((const f32x4*)in)[i];
  short4v o;
#pragma unroll
  for (int j = 0; j < 4; j++) o[j] = (short)f2bf(v[j]);
  ((short4v*)out)[i] = o;
}

// ---------------- flat broadcast logits -> plogits[0..3] ----------------
__global__ __launch_bounds__(256) void bcast_logits(
    const float* __restrict__ src, float* __restrict__ dst) {
  const size_t n4 = (size_t)S_LEN * VOCAB / 4;
  for (size_t i = (size_t)blockIdx.x * 256 + threadIdx.x; i < n4;
       i += (size_t)gridDim.x * 256) {
    f32x4 v = ((const f32x4*)src)[i];
#pragma unroll
    for (int p = 0; p < NPROC; p++)
      ((f32x4*)dst)[(size_t)p * n4 + i] = v;
  }
}

// ---------------- P=1 merge + LayerNorm -> bf16 (src = hidden at k=0, st1 after) --------
__global__ __launch_bounds__(256) void merge_ln_p1(
    const float* __restrict__ src, const int* __restrict__ mask,
    const float* __restrict__ alphap, const float* __restrict__ gamma,
    const float* __restrict__ beta, ushort* __restrict__ normed) {
  const int s = blockIdx.x;
  const int tid = threadIdx.x;
  const float mk = (float)mask[s];
  const float a1 = 1.0f + alphap[0];
  float merged[3];
  float lsum = 0.f, lsq = 0.f;
#pragma unroll
  for (int e = 0; e < 3; e++) {
    const int h = tid + e * 256;
    float mg = src[(size_t)s * HDIM + h] * mk * a1;
    merged[e] = mg;
    lsum += mg;
    lsq += mg * mg;
  }
#pragma unroll
  for (int off = 32; off > 0; off >>= 1) {
    lsum += __shfl_down(lsum, off, 64);
    lsq  += __shfl_down(lsq, off, 64);
  }
  __shared__ float rs_[4], rq_[4];
  const int wv = tid >> 6, ln = tid & 63;
  if (ln == 0) { rs_[wv] = lsum; rq_[wv] = lsq; }
  __syncthreads();
  const float ts = rs_[0] + rs_[1] + rs_[2] + rs_[3];
  const float tq = rq_[0] + rq_[1] + rq_[2] + rq_[3];
  const float mu = ts * (1.f / HDIM);
  const float var = tq * (1.f / HDIM) - mu * mu;
  const float rstd = rsqrtf(var + 1e-5f);
#pragma unroll
  for (int e = 0; e < 3; e++) {
    const int h = tid + e * 256;
    float nv = (merged[e] - mu) * rstd * gamma[h] + beta[h];
    normed[(size_t)s * HDIM + h] = f2bf(nv);
  }
}

// ---------------- MLP GEMM  C[M=1024,N=768] = A * B^T, 128x64 tile, BK=32 ----------------
// MODE 0: +b1, exact GELU -> bf16 h
// MODE 1: +b2, ns = (src*mask + C)*mask; normally dst=st1; on last k-step (out_bf set)
//         writes bf16(ns) to out_bf AND replicates ns into states[0..3] (fused expand).
template <int MODE>
__global__ __launch_bounds__(256, 4) void gemm_mlp(
    const ushort* __restrict__ A, const ushort* __restrict__ B,
    const float* __restrict__ bias, ushort* __restrict__ out_bf,
    const float* __restrict__ src, float* __restrict__ dst,
    float* __restrict__ states, const int* __restrict__ mask) {
  __shared__ __align__(16) ushort lsA[2][4096];  // [128][32]
  __shared__ __align__(16) ushort lsB[2][2048];  // [64][32]
  const int tid = threadIdx.x;
  const int bx = blockIdx.x;
  const int mt = bx & 7;    // M=1024 -> 8 m-tiles
  const int nt = bx >> 3;   // 12 n-tiles of 64
  const int wv = tid >> 6, lane = tid & 63;
  const int wm = wv >> 1, wn = wv & 1;
  const int g = lane >> 4, lr = lane & 15;

  f32x4 acc[4][2];
#pragma unroll
  for (int i = 0; i < 4; i++)
#pragma unroll
    for (int j = 0; j < 2; j++) acc[i][j] = (f32x4){0.f, 0.f, 0.f, 0.f};

  const int koff = (tid & 3) * 8;
  const int arow0 = mt * 128 + (tid >> 2);
  const ushort* gA0 = A + (size_t)arow0 * HDIM + koff;
  const ushort* gA1 = gA0 + (size_t)64 * HDIM;
  const ushort* gB0 = B + (size_t)(nt * 64 + (tid >> 2)) * HDIM + koff;
  const int dstl = (tid >> 2) * 32 + (tid & 3) * 8;

#define STAGE(kt, buf) do {                      \
    const int o_ = (kt) * 32;                    \
    GLOAD16(gA0 + o_, &lsA[buf][dstl]);          \
    GLOAD16(gA1 + o_, &lsA[buf][2048 + dstl]);   \
    GLOAD16(gB0 + o_, &lsB[buf][dstl]);          \
  } while (0)

  constexpr int NT = HDIM / 32;
  STAGE(0, 0);
  STAGE(1, 1);
  int cur = 0;
  for (int kt = 0; kt < NT; ++kt) {
    if (kt < NT - 1) asm volatile("s_waitcnt vmcnt(3)" ::: "memory");
    else             asm volatile("s_waitcnt vmcnt(0)" ::: "memory");
    __builtin_amdgcn_s_barrier();
    __builtin_amdgcn_sched_barrier(0);
    bf16x8 af[4], bfr[2];
#pragma unroll
    for (int mi = 0; mi < 4; mi++)
      af[mi] = *(const bf16x8*)(&lsA[cur][(wm * 64 + mi * 16 + lr) * 32 + g * 8]);
#pragma unroll
    for (int ni = 0; ni < 2; ni++)
      bfr[ni] = *(const bf16x8*)(&lsB[cur][(wn * 32 + ni * 16 + lr) * 32 + g * 8]);
    asm volatile("s_waitcnt lgkmcnt(0)" ::: "memory");
    __builtin_amdgcn_sched_barrier(0);
    __builtin_amdgcn_s_setprio(1);
#pragma unroll
    for (int mi = 0; mi < 4; mi++)
#pragma unroll
      for (int ni = 0; ni < 2; ni++)
        acc[mi][ni] = __builtin_amdgcn_mfma_f32_16x16x32_bf16(af[mi], bfr[ni], acc[mi][ni], 0, 0, 0);
    __builtin_amdgcn_s_setprio(0);
    __builtin_amdgcn_s_barrier();
    __builtin_amdgcn_sched_barrier(0);
    if (kt + 2 < NT) STAGE(kt + 2, cur);
    cur ^= 1;
  }
#undef STAGE

#pragma unroll
  for (int mi = 0; mi < 4; mi++) {
    const int mrow = mt * 128 + wm * 64 + mi * 16 + g * 4;
#pragma unroll
    for (int ni = 0; ni < 2; ni++) {
      const int ncol = nt * 64 + wn * 32 + ni * 16 + lr;
      const float bv = bias[ncol];
      if (MODE == 0) {
#pragma unroll
        for (int j = 0; j < 4; j++) {
          float x = acc[mi][ni][j] + bv;
          float ge = 0.5f * x * (1.f + erff(x * 0.70710678118654752f));
          out_bf[(size_t)(mrow + j) * HDIM + ncol] = f2bf(ge);
        }
      } else {
#pragma unroll
        for (int j = 0; j < 4; j++) {
          const int m = mrow + j;   // m == s at P=1
          const float mk = (float)mask[m];
          const size_t idx = (size_t)m * HDIM + ncol;
          const float mut = src[idx] * mk;
          const float ns = (mut + acc[mi][ni][j] + bv) * mk;
          if (out_bf) {
            out_bf[idx] = f2bf(ns);            // bf16 A for LM head
#pragma unroll
            for (int p = 0; p < NPROC; p++)    // fused expand -> d_out states[p]
              states[(size_t)p * S_LEN * HDIM + idx] = ns;
          } else {
            dst[idx] = ns;
          }
        }
      }
    }
  }
}

// ---------------- LM-head GEMM (P=1): 256x256 tile, BK=64, 4-phase deep pipeline ----------
// C[1024, 50257] = A[1024,768] * B[50257,768]^T. 512 thr, 8 waves (2Mx4N), 128 KB LDS.
// r11-verified. Epilogue writes ONLY logits; plogits replicated by bcast_logits.
__global__ __launch_bounds__(512, 2) void gemm_lm(
    const ushort* __restrict__ A, const ushort* __restrict__ B,
    float* __restrict__ logits, int nrowsB) {
  __shared__ __align__(16) ushort lds[2][4][8192];
  ushort* ldsb = &lds[0][0][0];
  const int tid = threadIdx.x;
  const int bx = blockIdx.x;
  const int mt = bx & 3;
  const int nt = bx >> 2;
  const int wv = tid >> 6, lane = tid & 63;
  const int wm = wv >> 2, wn = wv & 3;
  const int g = lane >> 4, lr = lane & 15;

  f32x4 acc[8][4];
#pragma unroll
  for (int i = 0; i < 8; i++)
#pragma unroll
    for (int j = 0; j < 4; j++) acc[i][j] = (f32x4){0.f, 0.f, 0.f, 0.f};

  const ushort* gsrc[4][2];
#pragma unroll
  for (int j = 0; j < 2; j++) {
    const int c = j * 512 + wv * 64 + lane;
    const int qa = c >> 9, ra = (c >> 3) & 63, oa = (c & 7) ^ (ra & 7);
    gsrc[0][j] = A + (size_t)(mt * 256 + qa * 128 + ra) * HDIM + oa * 8;
    gsrc[1][j] = A + (size_t)(mt * 256 + qa * 128 + 64 + ra) * HDIM + oa * 8;
    const int qb = c >> 8, rb = (c >> 3) & 31, ob = (c & 7) ^ (rb & 7);
    int r2 = nt * 256 + qb * 64 + rb;      if (r2 >= nrowsB) r2 = nrowsB - 1;
    int r3 = nt * 256 + qb * 64 + 32 + rb; if (r3 >= nrowsB) r3 = nrowsB - 1;
    gsrc[2][j] = B + (size_t)r2 * HDIM + ob * 8;
    gsrc[3][j] = B + (size_t)r3 * HDIM + ob * 8;
  }
  const int a_lane = wm * 4096 + lr * 64;
  const int b_lane = wn * 2048 + lr * 64;
  int slot8[2];
  slot8[0] = ((0 + g) ^ (lr & 7)) * 8;
  slot8[1] = ((4 + g) ^ (lr & 7)) * 8;

#define STG(R_, tt_) do {                                                     \
    ushort* dst_ = ldsb + (size_t)((((tt_) & 1) * 4 + (R_)) * 8192 + wv * 512); \
    GLOAD16(gsrc[R_][0] + (size_t)(tt_) * 64, dst_);                          \
    GLOAD16(gsrc[R_][1] + (size_t)(tt_) * 64, dst_ + 4096);                   \
  } while (0)

#define MFMA_Q(MB, NB, AV, BV) do {                                           \
    __builtin_amdgcn_s_setprio(1);                                           \
    _Pragma("unroll")                                                        \
    for (int mi = 0; mi < 4; mi++)                                           \
      _Pragma("unroll")                                                      \
      for (int ni = 0; ni < 2; ni++)                                         \
        _Pragma("unroll")                                                    \
        for (int ks = 0; ks < 2; ks++)                                       \
          acc[(MB) + mi][(NB) + ni] = __builtin_amdgcn_mfma_f32_16x16x32_bf16( \
              AV[mi][ks], BV[ni][ks], acc[(MB) + mi][(NB) + ni], 0, 0, 0);   \
    __builtin_amdgcn_s_setprio(0);                                           \
  } while (0)

  constexpr int NT = HDIM / 64;
  STG(0, 0); STG(2, 0); STG(3, 0); STG(1, 0);
  asm volatile("s_waitcnt vmcnt(4)" ::: "memory");
  __builtin_amdgcn_sched_barrier(0);
  __builtin_amdgcn_s_barrier();

  bf16x8 af[4][2], blo[2][2], bhi[2][2];
  for (int t = 0; t < NT - 1; ++t) {
    const ushort* cp = ldsb + (size_t)(t & 1) * 32768;
#pragma unroll
    for (int mi = 0; mi < 4; mi++)
#pragma unroll
      for (int ks = 0; ks < 2; ks++)
        af[mi][ks] = *(const bf16x8*)(cp + a_lane + mi * 1024 + slot8[ks]);
#pragma unroll
    for (int ni = 0; ni < 2; ni++)
#pragma unroll
      for (int ks = 0; ks < 2; ks++)
        blo[ni][ks] = *(const bf16x8*)(cp + 16384 + b_lane + ni * 1024 + slot8[ks]);
    STG(0, t + 1);
    __builtin_amdgcn_s_barrier();
    asm volatile("s_waitcnt lgkmcnt(0)" ::: "memory");
    __builtin_amdgcn_sched_barrier(0);
    MFMA_Q(0, 0, af, blo);
    asm volatile("s_waitcnt vmcnt(4)" ::: "memory");
    __builtin_amdgcn_sched_barrier(0);
    __builtin_amdgcn_s_barrier();
#pragma unroll
    for (int ni = 0; ni < 2; ni++)
#pragma unroll
      for (int ks = 0; ks < 2; ks++)
        bhi[ni][ks] = *(const bf16x8*)(cp + 24576 + b_lane + ni * 1024 + slot8[ks]);
    STG(2, t + 1);
    __builtin_amdgcn_s_barrier();
    asm volatile("s_waitcnt lgkmcnt(0)" ::: "memory");
    __builtin_amdgcn_sched_barrier(0);
    MFMA_Q(0, 2, af, bhi);
    asm volatile("s_waitcnt vmcnt(4)" ::: "memory");
    __builtin_amdgcn_sched_barrier(0);
    __builtin_amdgcn_s_barrier();
#pragma unroll
    for (int mi = 0; mi < 4; mi++)
#pragma unroll
      for (int ks = 0; ks < 2; ks++)
        af[mi][ks] = *(const bf16x8*)(cp + 8192 + a_lane + mi * 1024 + slot8[ks]);
    STG(3, t + 1);
    __builtin_amdgcn_s_barrier();
    asm volatile("s_waitcnt lgkmcnt(0)" ::: "memory");
    __builtin_amdgcn_sched_barrier(0);
    MFMA_Q(4, 2, af, bhi);
    __builtin_amdgcn_s_barrier();
    STG(1, t + 1);
    __builtin_amdgcn_s_barrier();
    MFMA_Q(4, 0, af, blo);
    asm volatile("s_waitcnt vmcnt(4)" ::: "memory");
    __builtin_amdgcn_sched_barrier(0);
    __builtin_amdgcn_s_barrier();
  }
  {
    const int t = NT - 1;
    const ushort* cp = ldsb + (size_t)(t & 1) * 32768;
#pragma unroll
    for (int mi = 0; mi < 4; mi++)
#pragma unroll
      for (int ks = 0; ks < 2; ks++)
        af[mi][ks] = *(const bf16x8*)(cp + a_lane + mi * 1024 + slot8[ks]);
#pragma unroll
    for (int ni = 0; ni < 2; ni++)
#pragma unroll
      for (int ks = 0; ks < 2; ks++)
        blo[ni][ks] = *(const bf16x8*)(cp + 16384 + b_lane + ni * 1024 + slot8[ks]);
    __builtin_amdgcn_s_barrier();
    asm volatile("s_waitcnt lgkmcnt(0)" ::: "memory");
    __builtin_amdgcn_sched_barrier(0);
    MFMA_Q(0, 0, af, blo);
    asm volatile("s_waitcnt vmcnt(2)" ::: "memory");
    __builtin_amdgcn_sched_barrier(0);
    __builtin_amdgcn_s_barrier();
#pragma unroll
    for (int ni = 0; ni < 2; ni++)
#pragma unroll
      for (int ks = 0; ks < 2; ks++)
        bhi[ni][ks] = *(const bf16x8*)(cp + 24576 + b_lane + ni * 1024 + slot8[ks]);
    __builtin_amdgcn_s_barrier();
    asm volatile("s_waitcnt lgkmcnt(0)" ::: "memory");
    __builtin_amdgcn_sched_barrier(0);
    MFMA_Q(0, 2, af, bhi);
    asm volatile("s_waitcnt vmcnt(0)" ::: "memory");
    __builtin_amdgcn_sched_barrier(0);
    __builtin_amdgcn_s_barrier();
#pragma unroll
    for (int mi = 0; mi < 4; mi++)
#pragma unroll
      for (int ks = 0; ks < 2; ks++)
        af[mi][ks] = *(const bf16x8*)(cp + 8192 + a_lane + mi * 1024 + slot8[ks]);
    asm volatile("s_waitcnt lgkmcnt(0)" ::: "memory");
    __builtin_amdgcn_sched_barrier(0);
    MFMA_Q(4, 2, af, bhi);
    MFMA_Q(4, 0, af, blo);
  }
#undef STG
#undef MFMA_Q

  float* sc = ((float*)ldsb) + wv * 1024;
  const int ncol0 = nt * 256 + wn * 64;
  const bool fast = (ncol0 + 64) <= nrowsB;
#pragma unroll
  for (int mi = 0; mi < 8; mi++) {
    __syncthreads();
#pragma unroll
    for (int ni = 0; ni < 4; ni++)
#pragma unroll
      for (int j = 0; j < 4; j++)
        sc[(g * 4 + j) * 64 + ni * 16 + lr] = acc[mi][ni][j];
    __syncthreads();
    const int srow0 = mt * 256 + wm * 128 + mi * 16;
    const int c0 = ncol0 + lr * 4;
#pragma unroll
    for (int jj = 0; jj < 4; jj++) {
      const f32x4 v = *(const f32x4*)&sc[(g * 4 + jj) * 64 + lr * 4];
      const int s = srow0 + g * 4 + jj;
      if (fast) {
        *(f32x4*)&logits[(size_t)s * VOCAB + c0] = v;
      } else {
#pragma unroll
        for (int cc = 0; cc < 4; cc++)
          if (c0 + cc < nrowsB) logits[(size_t)s * VOCAB + c0 + cc] = v[cc];
      }
    }
  }
}

extern "C" void kernel_launch(void* const* d_in, const int* in_sizes, int n_in,
                              void* d_out, int out_size, void* d_ws, size_t ws_size,
                              hipStream_t stream) {
  const float* hidden = (const float*)d_in[0];
  const int*   mask   = (const int*)d_in[1];
  const float* alphap = (const float*)d_in[2];
  const float* gamma  = (const float*)d_in[3];
  const float* beta   = (const float*)d_in[4];
  const float* W1     = (const float*)d_in[5];
  const float* b1     = (const float*)d_in[6];
  const float* W2     = (const float*)d_in[7];
  const float* b2     = (const float*)d_in[8];
  const float* lmw    = (const float*)d_in[9];

  float* logits  = (float*)d_out;
  float* plogits = logits + (size_t)S_LEN * VOCAB;
  float* states  = plogits + (size_t)NPROC * S_LEN * VOCAB;

  uint8_t* ws = (uint8_t*)d_ws;
  ushort* lm_bf  = (ushort*)ws;                       // 77,194,752 B
  ushort* w1_bf  = (ushort*)(ws + 77194752);          // 1,179,648 B
  ushort* w2_bf  = (ushort*)(ws + 78374400);          // 1,179,648 B
  ushort* nrm_bf = (ushort*)(ws + 79554048);          // 1,572,864 B
  ushort* h_bf   = (ushort*)(ws + 81126912);          // 1,572,864 B
  ushort* a_bf   = (ushort*)(ws + 82699776);          // 1,572,864 B
  float*  st1    = (float*) (ws + 84272640);          // 3,145,728 B
  if (ws_size < 87418368) return;

  const int LMB = (VOCAB * HDIM / 4 + 255) / 256, WB = (HDIM * HDIM / 4 + 255) / 256;
  prep_weights<<<LMB + 2 * WB, 256, 0, stream>>>(lmw, W1, W2, lm_bf, w1_bf, w2_bf);

  for (int k = 0; k < KSTEPS; k++) {
    const float* src = (k == 0) ? hidden : st1;
    merge_ln_p1<<<S_LEN, 256, 0, stream>>>(src, mask, alphap, gamma, beta, nrm_bf);
    gemm_mlp<0><<<(HDIM / 64) * 8, 256, 0, stream>>>(
        nrm_bf, w1_bf, b1, h_bf, nullptr, nullptr, nullptr, mask);
    gemm_mlp<1><<<(HDIM / 64) * 8, 256, 0, stream>>>(
        h_bf, w2_bf, b2, (k == KSTEPS - 1) ? (ushort*)a_bf : nullptr,
        src, st1, states, mask);
  }
  gemm_lm<<<((VOCAB + 255) / 256) * 4, 512, 0, stream>>>(a_bf, lm_bf, logits, VOCAB);
  bcast_logits<<<2048, 256, 0, stream>>>(logits, plogits);
}